// Round 5
// baseline (1644.930 us; speedup 1.0000x reference)
//
#include <hip/hip_runtime.h>

#define BB 64
#define TT 2048
#define II 64
#define HH 256

typedef __fp16 h2_t __attribute__((ext_vector_type(2)));
typedef __fp16 h8_t __attribute__((ext_vector_type(8)));

#if __has_builtin(__builtin_amdgcn_fdot2)
#define FDOT2(a, b, c) __builtin_amdgcn_fdot2((a), (b), (c), false)
#else
__device__ __forceinline__ float FDOT2(h2_t a, h2_t b, float c) {
    return fmaf((float)a[0], (float)b[0], fmaf((float)a[1], (float)b[1], c));
}
#endif

// tanh(x) = 1 - 2/(e^{2x}+1); v_exp + v_rcp, correct limits at +-inf.
__device__ __forceinline__ float ftanh(float x) {
    float e = __expf(2.0f * x);
    return 1.0f - 2.0f * __builtin_amdgcn_rcpf(e + 1.0f);
}

// 0xB1 = quad_perm(1,0,3,2) = xor1 ; 0x4E = quad_perm(2,3,0,1) = xor2
// 0x141 = ROW_HALF_MIRROR (^7; == xor4 once bits0-1 uniform)
// 0x140 = ROW_MIRROR      (^15; == xor8 once bits0-2 uniform)
template <int CTRL>
__device__ __forceinline__ float dpp_add(float v) {
    int s = __builtin_amdgcn_update_dpp(0, __float_as_int(v), CTRL, 0xF, 0xF, true);
    return v + __int_as_float(s);
}
template <int PAT>  // 0x401F = xor16 (within 32-lane halves)
__device__ __forceinline__ float swz_add(float v) {
    int s = __builtin_amdgcn_ds_swizzle(__float_as_int(v), PAT);
    return v + __int_as_float(s);
}

// 1024 threads = 16 waves, 4/EU. fp16 weights: whh 32 + wih 8 VGPRs -> the
// whole working set (~80-100 regs) fits the 128-VGPR cap WITHOUT AGPR
// round-trips (R2/R3 lesson: fp32 weights at 80+ regs got split to AGPRs).
__launch_bounds__(1024, 4)
__global__ void rnn_fused(const float* __restrict__ x,
                          const float* __restrict__ W_ih,
                          const float* __restrict__ W_hh,
                          const float* __restrict__ b_ih,
                          const float* __restrict__ b_hh,
                          const float* __restrict__ W_fc,
                          const float* __restrict__ b_fc,
                          float* __restrict__ out) {
    // h in fp16, double-buffered. Physical layout: 32-half chunks at stride
    // 40 halves (80 B): haddr(t) = (t>>5)*40 + (t&31). Byte addr of slice q,
    // word jv: q*80 + jv*16 -> bank quad (q*20+jv*4)%32: q->{0,20,8,28,16,4,
    // 24,12} all disjoint -> conflict-free b128 broadcast reads.
    __shared__ __align__(16) __fp16 hbuf[2][320];
    __shared__ float wavepart[2][32];

    const int tid  = threadIdx.x;
    const int b    = blockIdx.x;
    const int lane = tid & 63;
    const int w    = tid >> 6;   // wave 0..15
    const int o    = lane >> 3;  // row sub-slot 0..7
    const int q    = lane & 7;   // k-slice 0..7

    // thread owns rows t_r = w*16 + r*8 + o (r=0,1), cols [q*32, q*32+32)
    h2_t whh[2][16];  // 32 VGPRs
    h2_t wih[2][4];   //  8 VGPRs
    float bias[2], wfcr[2];
#pragma unroll
    for (int r = 0; r < 2; ++r) {
        const int t_r = w * 16 + r * 8 + o;
        const float4* wr = (const float4*)(W_hh + t_r * HH + q * 32);
#pragma unroll
        for (int jv = 0; jv < 8; ++jv) {
            const float4 wv = wr[jv];
            whh[r][jv * 2 + 0] = __builtin_amdgcn_cvt_pkrtz(wv.x, wv.y);
            whh[r][jv * 2 + 1] = __builtin_amdgcn_cvt_pkrtz(wv.z, wv.w);
        }
        const float4* wi = (const float4*)(W_ih + t_r * II + q * 8);
        const float4 wa = wi[0], wb = wi[1];
        wih[r][0] = __builtin_amdgcn_cvt_pkrtz(wa.x, wa.y);
        wih[r][1] = __builtin_amdgcn_cvt_pkrtz(wa.z, wa.w);
        wih[r][2] = __builtin_amdgcn_cvt_pkrtz(wb.x, wb.y);
        wih[r][3] = __builtin_amdgcn_cvt_pkrtz(wb.z, wb.w);
        bias[r] = b_ih[t_r] + b_hh[t_r];
        wfcr[r] = W_fc[t_r];
    }
    const float bfc = b_fc[0];

    for (int idx = tid; idx < 2 * 320; idx += 1024) ((__fp16*)hbuf)[idx] = (__fp16)0.0f;
    __syncthreads();

    const float* xbase = x + (size_t)b * TT * II + q * 8;
    float* outb = out + (size_t)b * TT;

    // preload + convert x row 0
    h2_t xc[4];
    {
        const float4* xp = (const float4*)(xbase);
        const float4 a = xp[0], c = xp[1];
        xc[0] = __builtin_amdgcn_cvt_pkrtz(a.x, a.y);
        xc[1] = __builtin_amdgcn_cvt_pkrtz(a.z, a.w);
        xc[2] = __builtin_amdgcn_cvt_pkrtz(c.x, c.y);
        xc[3] = __builtin_amdgcn_cvt_pkrtz(c.z, c.w);
    }

    int p = 0;
    for (int i = 0; i < TT; ++i) {
        // kick off x prefetch for step i+1 (converted after the dot chain)
        const int rown = (i + 1 < TT) ? (i + 1) : (TT - 1);
        const float4* xpn = (const float4*)(xbase + rown * II);
        const float4 xna = xpn[0], xnc = xpn[1];

        // ---- recurrent dots: 2 rows x 32 cols, fp16 pairs, fp32 acc ----
        float a0a = 0.0f, a0b = 0.0f, a1a = 0.0f, a1b = 0.0f;
        const h8_t* hp = (const h8_t*)((const char*)&hbuf[p][0] + q * 80);
#pragma unroll
        for (int jv = 0; jv < 4; ++jv) {
            const h8_t hv = hp[jv];
            const h2_t p0 = __builtin_shufflevector(hv, hv, 0, 1);
            const h2_t p1 = __builtin_shufflevector(hv, hv, 2, 3);
            const h2_t p2 = __builtin_shufflevector(hv, hv, 4, 5);
            const h2_t p3 = __builtin_shufflevector(hv, hv, 6, 7);
            a0a = FDOT2(whh[0][jv * 4 + 0], p0, a0a);
            a0b = FDOT2(whh[0][jv * 4 + 1], p1, a0b);
            a0a = FDOT2(whh[0][jv * 4 + 2], p2, a0a);
            a0b = FDOT2(whh[0][jv * 4 + 3], p3, a0b);
            a1a = FDOT2(whh[1][jv * 4 + 0], p0, a1a);
            a1b = FDOT2(whh[1][jv * 4 + 1], p1, a1b);
            a1a = FDOT2(whh[1][jv * 4 + 2], p2, a1a);
            a1b = FDOT2(whh[1][jv * 4 + 3], p3, a1b);
        }
        // fused input projection (x already fp16 from prev iter's prefetch)
        a0a = FDOT2(wih[0][0], xc[0], a0a);
        a0b = FDOT2(wih[0][1], xc[1], a0b);
        a0a = FDOT2(wih[0][2], xc[2], a0a);
        a0b = FDOT2(wih[0][3], xc[3], a0b);
        a1a = FDOT2(wih[1][0], xc[0], a1a);
        a1b = FDOT2(wih[1][1], xc[1], a1b);
        a1a = FDOT2(wih[1][2], xc[2], a1a);
        a1b = FDOT2(wih[1][3], xc[3], a1b);
        float acc0 = a0a + a0b;
        float acc1 = a1a + a1b;

        // convert the prefetched x row (loads have landed by now)
        xc[0] = __builtin_amdgcn_cvt_pkrtz(xna.x, xna.y);
        xc[1] = __builtin_amdgcn_cvt_pkrtz(xna.z, xna.w);
        xc[2] = __builtin_amdgcn_cvt_pkrtz(xnc.x, xnc.y);
        xc[3] = __builtin_amdgcn_cvt_pkrtz(xnc.z, xnc.w);

        // all-reduce over the 8 k-slices (lane bits 0..2) — pure DPP
        acc0 = dpp_add<0xB1>(acc0);
        acc0 = dpp_add<0x4E>(acc0);
        acc0 = dpp_add<0x141>(acc0);
        acc1 = dpp_add<0xB1>(acc1);
        acc1 = dpp_add<0x4E>(acc1);
        acc1 = dpp_add<0x141>(acc1);

        const float h0 = ftanh(acc0 + bias[0]);
        const float h1 = ftanh(acc1 + bias[1]);

        const int pn = p ^ 1;
        if (q == 0) {
            const int t0 = w * 16 + o;
            const int t1 = t0 + 8;
            hbuf[pn][(t0 >> 5) * 40 + (t0 & 31)] = (__fp16)h0;
            hbuf[pn][(t1 >> 5) * 40 + (t1 & 31)] = (__fp16)h1;
        }

        // output head partial (uniform across q): reduce over o, stage 32
        float c = fmaf(h1, wfcr[1], h0 * wfcr[0]);
        c = dpp_add<0x140>(c);    // ^8 (bits0-2 uniform)
        c = swz_add<0x401F>(c);   // ^16
        if ((lane & 31) == 0) wavepart[pn][w * 2 + (lane >> 5)] = c;

        __syncthreads();  // ONE barrier: h_{i+1} + waveparts visible

        // previous step's scalar output, off the critical path (wave 0 only)
        if (w == 0 && i > 0) {
            float s2 = wavepart[p][lane & 31];
            s2 = dpp_add<0xB1>(s2);
            s2 = dpp_add<0x4E>(s2);
            s2 = dpp_add<0x141>(s2);
            s2 = dpp_add<0x140>(s2);
            s2 = swz_add<0x401F>(s2);
            if (lane == 0) outb[i - 1] = s2 + bfc;
        }
        p = pn;
    }
    __syncthreads();
    if (w == 0) {
        float s2 = wavepart[p][lane & 31];
        s2 = dpp_add<0xB1>(s2);
        s2 = dpp_add<0x4E>(s2);
        s2 = dpp_add<0x141>(s2);
        s2 = dpp_add<0x140>(s2);
        s2 = swz_add<0x401F>(s2);
        if (lane == 0) outb[TT - 1] = s2 + bfc;
    }
}

extern "C" void kernel_launch(void* const* d_in, const int* in_sizes, int n_in,
                              void* d_out, int out_size, void* d_ws, size_t ws_size,
                              hipStream_t stream) {
    const float* x    = (const float*)d_in[0];
    const float* W_ih = (const float*)d_in[1];
    const float* W_hh = (const float*)d_in[2];
    const float* b_ih = (const float*)d_in[3];
    const float* b_hh = (const float*)d_in[4];
    const float* W_fc = (const float*)d_in[5];
    const float* b_fc = (const float*)d_in[6];
    float* out = (float*)d_out;

    rnn_fused<<<BB, 1024, 0, stream>>>(x, W_ih, W_hh, b_ih, b_hh, W_fc, b_fc, out);
}

// Round 6
// 1322.783 us; speedup vs baseline: 1.2435x; 1.2435x over previous
//
#include <hip/hip_runtime.h>

#define BB 64
#define TT 2048
#define II 64
#define HH 256

typedef __fp16 h2_t __attribute__((ext_vector_type(2)));
typedef __fp16 h8_t __attribute__((ext_vector_type(8)));

#define H2(i) __builtin_bit_cast(h2_t, (i))
#define I32(h) __builtin_bit_cast(int, (h))

#if __has_builtin(__builtin_amdgcn_fdot2)
#define FDOT2(a, b, c) __builtin_amdgcn_fdot2((a), (b), (c), false)
#else
__device__ __forceinline__ float FDOT2(h2_t a, h2_t b, float c) {
    return fmaf((float)a[0], (float)b[0], fmaf((float)a[1], (float)b[1], c));
}
#endif

// tanh(x) = 1 - 2/(e^{2x}+1); v_exp + v_rcp, correct limits at +-inf.
__device__ __forceinline__ float ftanh(float x) {
    float e = __expf(2.0f * x);
    return 1.0f - 2.0f * __builtin_amdgcn_rcpf(e + 1.0f);
}

// 0xB1 = quad_perm xor1, 0x4E = quad_perm xor2, 0x140 = ROW_MIRROR (^15)
template <int CTRL>
__device__ __forceinline__ float dpp_add(float v) {
    int s = __builtin_amdgcn_update_dpp(0, __float_as_int(v), CTRL, 0xF, 0xF, true);
    return v + __int_as_float(s);
}
template <int CTRL>
__device__ __forceinline__ float dpp_get(float v) {
    int s = __builtin_amdgcn_update_dpp(0, __float_as_int(v), CTRL, 0xF, 0xF, true);
    return __int_as_float(s);
}
// true lane^4 / lane^16 exchange via ds_swizzle (works on arbitrary data)
template <int PAT>  // 0x101F = xor4, 0x401F = xor16
__device__ __forceinline__ float swz_get(float v) {
    return __int_as_float(__builtin_amdgcn_ds_swizzle(__float_as_int(v), PAT));
}
template <int PAT>
__device__ __forceinline__ float swz_add(float v) { return v + swz_get<PAT>(v); }

// merge-reduce: lo-lane keeps sum of a over the bit-pair, hi-lane keeps b.
__device__ __forceinline__ float mrg4(float a, float b, int lane) {
    float t = (lane & 4) ? b : a;
    float u = (lane & 4) ? a : b;
    return t + swz_get<0x101F>(u);
}
__device__ __forceinline__ float mrg2(float a, float b, int lane) {
    float t = (lane & 2) ? b : a;
    float u = (lane & 2) ? a : b;
    return t + dpp_get<0x4E>(u);
}
__device__ __forceinline__ float mrg1(float a, float b, int lane) {
    float t = (lane & 1) ? b : a;
    float u = (lane & 1) ? a : b;
    return t + dpp_get<0xB1>(u);
}

// 256 threads = 4 waves, 1 wave/SIMD. launch_bounds(256,1) -> 512-VGPR budget
// so the pinned fp16 weight tile (~160 regs) stays in architectural VGPRs.
// R2-R5 lesson: the compiler SINKS loop-invariant weight loads into the loop
// (re-fetching from L2 every step, VGPR_Count 52-104); asm-pin forbids that.
__launch_bounds__(256, 1)
__global__ void rnn_fused(const float* __restrict__ x,
                          const float* __restrict__ W_ih,
                          const float* __restrict__ W_hh,
                          const float* __restrict__ b_ih,
                          const float* __restrict__ b_hh,
                          const float* __restrict__ W_fc,
                          const float* __restrict__ b_fc,
                          float* __restrict__ out) {
    // h fp16, double-buffered; 32-half chunks at 80 B stride: chunk q word jv
    // hits bank quad (20q+4jv)%32, q->{0,20,8,28,16,4,24,12} disjoint ->
    // conflict-free b128 broadcast reads.
    __shared__ __align__(16) __fp16 hbuf[2][320];
    __shared__ float part[TT][8];  // per-step head partials (summed post-loop)

    const int tid  = threadIdx.x;
    const int b    = blockIdx.x;
    const int lane = tid & 63;
    const int w    = tid >> 6;   // wave 0..3
    const int o    = lane >> 3;  // row sub-slot 0..7
    const int q    = lane & 7;   // k-slice 0..7

    // thread owns rows w*64 + o*8 + r (r=0..7), cols [q*32, q*32+32)
    int whh_i[8][16];  // 128 VGPRs (fp16 pairs as int)
    int wih_i[8][4];   //  32 VGPRs
#pragma unroll
    for (int r = 0; r < 8; ++r) {
        const int t_r = w * 64 + o * 8 + r;
        const float4* wr = (const float4*)(W_hh + t_r * HH + q * 32);
#pragma unroll
        for (int jv = 0; jv < 8; ++jv) {
            const float4 wv = wr[jv];
            whh_i[r][jv * 2 + 0] = I32(__builtin_amdgcn_cvt_pkrtz(wv.x, wv.y));
            whh_i[r][jv * 2 + 1] = I32(__builtin_amdgcn_cvt_pkrtz(wv.z, wv.w));
        }
        const float4* wi = (const float4*)(W_ih + t_r * II + q * 8);
        const float4 wa = wi[0], wb = wi[1];
        wih_i[r][0] = I32(__builtin_amdgcn_cvt_pkrtz(wa.x, wa.y));
        wih_i[r][1] = I32(__builtin_amdgcn_cvt_pkrtz(wa.z, wa.w));
        wih_i[r][2] = I32(__builtin_amdgcn_cvt_pkrtz(wb.x, wb.y));
        wih_i[r][3] = I32(__builtin_amdgcn_cvt_pkrtz(wb.z, wb.w));
    }
    // pin weights into VGPRs: asm def cannot be rematerialized from memory
#pragma unroll
    for (int j = 0; j < 128; ++j) asm volatile("" : "+v"(((int*)whh_i)[j]));
#pragma unroll
    for (int j = 0; j < 32; ++j) asm volatile("" : "+v"(((int*)wih_i)[j]));

    const int myrow = w * 64 + lane;  // the row this lane owns post-reduce
    const float bias = b_ih[myrow] + b_hh[myrow];
    const float wfc  = W_fc[myrow];
    const float bfc  = b_fc[0];

    for (int idx = tid; idx < 2 * 320; idx += 256) ((__fp16*)hbuf)[idx] = (__fp16)0.0f;
    __syncthreads();

    const float* xbase = x + (size_t)b * TT * II + q * 8;
    float* outb = out + (size_t)b * TT;

    // h write address: chunk (w*2 + lane/32), offset lane%32 halves
    const int hoff = (w * 2 + (lane >> 5)) * 80 + (lane & 31) * 2;  // bytes
    __fp16* hw0 = (__fp16*)((char*)&hbuf[0][0] + hoff);
    __fp16* hw1 = (__fp16*)((char*)&hbuf[1][0] + hoff);

    // preload + convert x row 0
    h2_t xc[4];
    {
        const float4* xp = (const float4*)(xbase);
        const float4 a = xp[0], c = xp[1];
        xc[0] = __builtin_amdgcn_cvt_pkrtz(a.x, a.y);
        xc[1] = __builtin_amdgcn_cvt_pkrtz(a.z, a.w);
        xc[2] = __builtin_amdgcn_cvt_pkrtz(c.x, c.y);
        xc[3] = __builtin_amdgcn_cvt_pkrtz(c.z, c.w);
    }

    int p = 0;
    for (int i = 0; i < TT; ++i) {
        // prefetch x row i+1 (consumed next iter; converted after the dots)
        const int rown = (i + 1 < TT) ? (i + 1) : (TT - 1);
        const float4* xpn = (const float4*)(xbase + rown * II);
        const float4 xna = xpn[0], xnc = xpn[1];

        // ---- dots: 8 rows x 32-col slice + 8-col input proj ----
        float a0 = 0, a1 = 0, a2 = 0, a3 = 0, a4 = 0, a5 = 0, a6 = 0, a7 = 0;
        const h8_t* hp = (const h8_t*)((const char*)&hbuf[p][0] + q * 80);
#pragma unroll
        for (int jv = 0; jv < 4; ++jv) {
            const h8_t hv = hp[jv];
#pragma unroll
            for (int e = 0; e < 4; ++e) {
                const h2_t hh2 = __builtin_shufflevector(hv, hv, 0, 1);
                const h2_t he = (e == 0) ? __builtin_shufflevector(hv, hv, 0, 1)
                              : (e == 1) ? __builtin_shufflevector(hv, hv, 2, 3)
                              : (e == 2) ? __builtin_shufflevector(hv, hv, 4, 5)
                                         : __builtin_shufflevector(hv, hv, 6, 7);
                const int j = jv * 4 + e;
                a0 = FDOT2(H2(whh_i[0][j]), he, a0);
                a1 = FDOT2(H2(whh_i[1][j]), he, a1);
                a2 = FDOT2(H2(whh_i[2][j]), he, a2);
                a3 = FDOT2(H2(whh_i[3][j]), he, a3);
                a4 = FDOT2(H2(whh_i[4][j]), he, a4);
                a5 = FDOT2(H2(whh_i[5][j]), he, a5);
                a6 = FDOT2(H2(whh_i[6][j]), he, a6);
                a7 = FDOT2(H2(whh_i[7][j]), he, a7);
                (void)hh2;
            }
        }
#pragma unroll
        for (int e = 0; e < 4; ++e) {
            a0 = FDOT2(H2(wih_i[0][e]), xc[e], a0);
            a1 = FDOT2(H2(wih_i[1][e]), xc[e], a1);
            a2 = FDOT2(H2(wih_i[2][e]), xc[e], a2);
            a3 = FDOT2(H2(wih_i[3][e]), xc[e], a3);
            a4 = FDOT2(H2(wih_i[4][e]), xc[e], a4);
            a5 = FDOT2(H2(wih_i[5][e]), xc[e], a5);
            a6 = FDOT2(H2(wih_i[6][e]), xc[e], a6);
            a7 = FDOT2(H2(wih_i[7][e]), xc[e], a7);
        }

        // convert prefetched x (loads have landed under the dot chain)
        xc[0] = __builtin_amdgcn_cvt_pkrtz(xna.x, xna.y);
        xc[1] = __builtin_amdgcn_cvt_pkrtz(xna.z, xna.w);
        xc[2] = __builtin_amdgcn_cvt_pkrtz(xnc.x, xnc.y);
        xc[3] = __builtin_amdgcn_cvt_pkrtz(xnc.z, xnc.w);

        // ---- merge-reduce across the 8 k-slices: lane ends owning row=lane
        const float A0 = mrg4(a0, a4, lane);
        const float A1 = mrg4(a1, a5, lane);
        const float A2 = mrg4(a2, a6, lane);
        const float A3 = mrg4(a3, a7, lane);
        const float B0 = mrg2(A0, A2, lane);
        const float B1 = mrg2(A1, A3, lane);
        const float C0 = mrg1(B0, B1, lane);

        const float hn = ftanh(C0 + bias);
        const int pn = p ^ 1;
        // h write: all 64 lanes, 2B each, 2 lanes/bank-word (free)
        if (pn) hw1[0] = (__fp16)hn; else hw0[0] = (__fp16)hn;

        // head partial: full-wave reduce of h*wfc, store 2 half-sums
        float c = hn * wfc;
        c = dpp_add<0xB1>(c);
        c = dpp_add<0x4E>(c);
        c = swz_add<0x101F>(c);
        c = dpp_add<0x140>(c);   // ^8 (bits0-2 now uniform)
        c = swz_add<0x401F>(c);  // ^16
        if ((lane & 31) == 0) part[i][w * 2 + (lane >> 5)] = c;

        __syncthreads();  // ONE barrier: h_{i+1} + part visible
        p = pn;
    }

    // ---- deferred output head: out[b][i] = sum(part[i][:]) + bfc ----
    for (int i = tid; i < TT; i += 256) {
        const float4* pp = (const float4*)&part[i][0];
        const float4 s0 = pp[0], s1 = pp[1];
        outb[i] = s0.x + s0.y + s0.z + s0.w + s1.x + s1.y + s1.z + s1.w + bfc;
    }
}

extern "C" void kernel_launch(void* const* d_in, const int* in_sizes, int n_in,
                              void* d_out, int out_size, void* d_ws, size_t ws_size,
                              hipStream_t stream) {
    const float* x    = (const float*)d_in[0];
    const float* W_ih = (const float*)d_in[1];
    const float* W_hh = (const float*)d_in[2];
    const float* b_ih = (const float*)d_in[3];
    const float* b_hh = (const float*)d_in[4];
    const float* W_fc = (const float*)d_in[5];
    const float* b_fc = (const float*)d_in[6];
    float* out = (float*)d_out;

    rnn_fused<<<BB, 256, 0, stream>>>(x, W_ih, W_hh, b_ih, b_hh, W_fc, b_fc, out);
}